// Round 8
// baseline (142.799 us; speedup 1.0000x reference)
//
#include <hip/hip_runtime.h>
#include <stdint.h>

#define NND 4096
#define DIM 1024      // D = GC1 = GC2
#define FC1N 512

typedef __attribute__((ext_vector_type(8))) short short8;
typedef __attribute__((ext_vector_type(4))) float floatx4;
typedef unsigned short u16;
typedef unsigned int u32;

__device__ __forceinline__ u16 f2bf(float f) {
    union { float f; u32 u; } a; a.f = f;
    u32 u = a.u;
    return (u16)((u + 0x7fffu + ((u >> 16) & 1u)) >> 16);   // RNE
}
__device__ __forceinline__ float bf2f(u16 h) {
    union { u32 u; float f; } a; a.u = ((u32)h) << 16; return a.f;
}
__device__ __forceinline__ float selu_f(float x) {
    const float lam = 1.0507009873554805f;
    const float alp = 1.6732632423543772f;
    return x > 0.f ? lam * x : lam * alp * (expf(x) - 1.f);
}
__device__ __forceinline__ void async16(const u16* g, u16* l) {
    __builtin_amdgcn_global_load_lds((const __attribute__((address_space(1))) u32*)g,
                                     (__attribute__((address_space(3))) u32*)l, 16, 0, 0);
}
// 1/sqrt(deg) for row i of the banded adjacency; 0 for out-of-range rows
__device__ __forceinline__ float dinv_row(int i, const float* fw, const float* bw) {
    if (i < 0 || i >= NND) return 0.f;
    float deg = 1.f;
    #pragma unroll
    for (int j = 0; j < 8; ++j) {
        if (i + j + 1 < NND) deg += fw[j];
        if (i - j - 1 >= 0)  deg += bw[j];
    }
    return 1.f / sqrtf(deg);
}

// ---- prep --------------------------------------------------------------------
// blocks 0..511   : XA = Ahat @ X (fp32 -> bf16), 32 rows x 256 cols per block
//                   (48-row input tile: 1.5x read amp vs 2x at 16-row blocks)
// blocks 512..1023: W1/W2 transpose [K][N]fp32 -> [N][K]bf16, 64x64 tiles
// block 1024      : zero pooled/zacc/cnt
// blocks 1025..1040: rs[i] = rowsum(Ahat), 256 rows per block (parallel)
__global__ void k_prep(const float* __restrict__ x, const float* __restrict__ w1,
                       const float* __restrict__ w2, const float* __restrict__ fw,
                       const float* __restrict__ bw, u16* __restrict__ XA,
                       u16* __restrict__ W1t, u16* __restrict__ W2t,
                       float* __restrict__ fzone) {
    __shared__ __align__(16) char smem[49152];
    int b = blockIdx.x, t = threadIdx.x;
    if (b < 512) {                                   // row-band stencil on X
        __shared__ float sdv_s[48];
        __shared__ float wts_s[17];
        int m0 = (b >> 2) * 32;
        int c0 = (b & 3) * 256;
        if (t < 48) sdv_s[t] = dinv_row(m0 - 8 + t, fw, bw);
        else if (t >= 64 && t < 81) {
            int o = t - 72;                          // -8..8
            wts_s[t - 64] = (o == 0) ? 1.f : (o > 0 ? fw[o - 1] : bw[-o - 1]);
        }
        float (*tile)[256] = (float(*)[256])smem;    // 48 rows x 256 cols fp32
        int seg = t & 7;
        {
            int row = t >> 3;                        // rows 0..31
            int g = m0 - 8 + row;
            g = g < 0 ? 0 : (g > NND - 1 ? NND - 1 : g);
            const float4* src = (const float4*)x + (size_t)g * 256 + (c0 >> 2);
            float4* trow = (float4*)tile[row];
            #pragma unroll
            for (int i = 0; i < 8; ++i) trow[seg + i * 8] = src[seg + i * 8];
        }
        if (t < 128) {
            int row = 32 + (t >> 3);                 // rows 32..47
            int g = m0 - 8 + row;
            g = g > NND - 1 ? NND - 1 : g;
            const float4* src = (const float4*)x + (size_t)g * 256 + (c0 >> 2);
            float4* trow = (float4*)tile[row];
            #pragma unroll
            for (int i = 0; i < 8; ++i) trow[seg + i * 8] = src[seg + i * 8];
        }
        __syncthreads();
        float w[17];
        #pragma unroll
        for (int o = 0; o < 17; ++o) w[o] = wts_s[o];
        float win[17];
        #pragma unroll
        for (int j = 0; j < 16; ++j) win[j] = sdv_s[j] * tile[j][t];
        #pragma unroll
        for (int rr = 0; rr < 32; ++rr) {
            win[(rr + 16) % 17] = sdv_s[rr + 16] * tile[rr + 16][t];
            float a = 0.f;
            #pragma unroll
            for (int o = 0; o < 17; ++o) a += w[o] * win[(rr + o) % 17];
            XA[(size_t)(m0 + rr) * DIM + c0 + t] = f2bf(a * sdv_s[8 + rr]);
        }
        return;
    }
    if (b == 1024) {                                 // zero scratch floats
        for (int i = t; i < 1537; i += 256) fzone[i] = 0.f;   // pooled+zacc+cnt
        return;
    }
    if (b >= 1025) {                                 // rs: 256 rows per block
        float* rs = fzone + 2048;
        float fwr[8], bwr[8];
        #pragma unroll
        for (int j = 0; j < 8; ++j) { fwr[j] = fw[j]; bwr[j] = bw[j]; }
        float* dv = (float*)smem;                    // dinv for i0-8 .. i0+263
        int i0 = (b - 1025) * 256;
        #pragma unroll
        for (int half = 0; half < 2; ++half) {
            int idx = t + half * 256;                // 0..511; need 0..271
            if (idx < 272) {
                int i = i0 - 8 + idx;
                float dvv = 0.f;
                if (i >= 0 && i < NND) {
                    float deg = 1.f;
                    #pragma unroll
                    for (int j = 0; j < 8; ++j) {
                        if (i + j + 1 < NND) deg += fwr[j];
                        if (i - j - 1 >= 0)  deg += bwr[j];
                    }
                    dvv = 1.f / sqrtf(deg);
                }
                dv[idx] = dvv;
            }
        }
        __syncthreads();
        float di = dv[t + 8];
        float s = di;
        #pragma unroll
        for (int k = 1; k <= 8; ++k)
            s += fwr[k - 1] * dv[t + 8 + k] + bwr[k - 1] * dv[t + 8 - k];
        rs[i0 + t] = di * s;
        return;
    }
    // transpose [K][N] fp32 -> [N][K] bf16, 64x64 tiles
    int job = b - 512;
    const float* in = (job & 256) ? w2 : w1;
    u16* out = (job & 256) ? W2t : W1t;
    int tl = job & 255;
    int r0 = (tl >> 4) * 64, c0 = (tl & 15) * 64;
    float (*tile)[65] = (float(*)[65])smem;          // 64x65 fp32 = 16.6 KB
    int cg = t & 15, rb = t >> 4;
    #pragma unroll
    for (int rr = 0; rr < 4; ++rr) {
        int row = rb + rr * 16;
        float4 v = *(const float4*)(in + (size_t)(r0 + row) * DIM + c0 + cg * 4);
        tile[row][cg * 4 + 0] = v.x; tile[row][cg * 4 + 1] = v.y;
        tile[row][cg * 4 + 2] = v.z; tile[row][cg * 4 + 3] = v.w;
    }
    __syncthreads();
    #pragma unroll
    for (int rr = 0; rr < 4; ++rr) {
        int nl = rb + rr * 16;
        int kl = cg * 4;
        ushort4 o;
        o.x = f2bf(tile[kl + 0][nl]); o.y = f2bf(tile[kl + 1][nl]);
        o.z = f2bf(tile[kl + 2][nl]); o.w = f2bf(tile[kl + 3][nl]);
        *(ushort4*)(out + (size_t)(c0 + nl) * DIM + r0 + kl) = o;
    }
}

// ---- band stencil on bf16 matrix: out = Ahat @ in  (between the two GEMMs) --
// 32 output rows x 256 cols per block (48-row input tile), grid 512.
__global__ void k_band(const u16* __restrict__ in, u16* __restrict__ outp,
                       const float* __restrict__ fw, const float* __restrict__ bw) {
    __shared__ __align__(16) u16 tile[48][256];      // 24 KB
    __shared__ float sdv_s[48];
    __shared__ float wts_s[17];
    int b = blockIdx.x, t = threadIdx.x;
    int m0 = (b >> 2) * 32;
    int c0 = (b & 3) * 256;
    if (t < 48) sdv_s[t] = dinv_row(m0 - 8 + t, fw, bw);
    else if (t >= 64 && t < 81) {
        int o = t - 72;
        wts_s[t - 64] = (o == 0) ? 1.f : (o > 0 ? fw[o - 1] : bw[-o - 1]);
    }
    int seg = t & 7;
    {
        int row = t >> 3;                            // rows 0..31
        int g = m0 - 8 + row;
        g = g < 0 ? 0 : (g > NND - 1 ? NND - 1 : g);
        const uint4* src = (const uint4*)(in + (size_t)g * DIM + c0);
        uint4* trow = (uint4*)tile[row];
        #pragma unroll
        for (int i = 0; i < 4; ++i) trow[seg + i * 8] = src[seg + i * 8];
    }
    if (t < 128) {
        int row = 32 + (t >> 3);                     // rows 32..47
        int g = m0 - 8 + row;
        g = g > NND - 1 ? NND - 1 : g;
        const uint4* src = (const uint4*)(in + (size_t)g * DIM + c0);
        uint4* trow = (uint4*)tile[row];
        #pragma unroll
        for (int i = 0; i < 4; ++i) trow[seg + i * 8] = src[seg + i * 8];
    }
    __syncthreads();
    float w[17];
    #pragma unroll
    for (int o = 0; o < 17; ++o) w[o] = wts_s[o];
    float win[17];
    #pragma unroll
    for (int j = 0; j < 16; ++j) win[j] = sdv_s[j] * bf2f(tile[j][t]);
    #pragma unroll
    for (int rr = 0; rr < 32; ++rr) {
        win[(rr + 16) % 17] = sdv_s[rr + 16] * bf2f(tile[rr + 16][t]);
        float a = 0.f;
        #pragma unroll
        for (int o = 0; o < 17; ++o) a += w[o] * win[(rr + o) % 17];
        outp[(size_t)(m0 + rr) * DIM + c0 + t] = f2bf(a * sdv_s[8 + rr]);
    }
}

// ---- 128x64 bf16 GEMM tile, double-buffered, plain __syncthreads ------------
// H[m,n] = selu(acc + rs[m]*bias[n]). mode 0: write bf16 H. mode 1: mean-pool.
// Grid (32,16)=512 blocks = 2 blocks/CU (launch_bounds 256,2; 48 KB LDS x2 =
// 96 KB <= 160 KB). Cross-block wave overlap (m114) hides the barrier drain —
// no inline asm anywhere (harness-proven sync structure, round 7: 142.5 us).
// 4 waves 2Mx2N (wave tile 64x32, acc 4x2). BK=64, prefetch k+1 into buf^1.
__launch_bounds__(256, 2)
__global__ void k_gemm(const u16* __restrict__ A, const u16* __restrict__ Bt,
                       const float* __restrict__ bias, const float* __restrict__ rs,
                       u16* __restrict__ H, float* __restrict__ pooled, int mode) {
    __shared__ __align__(16) u16 stage[2][12288];   // 2 x (A 128x64 | B 64x64) = 48 KB
    const int m0 = blockIdx.x * 128, n0 = blockIdx.y * 64;
    const int t = threadIdx.x, wave = t >> 6, lane = t & 63;
    const int q = lane >> 4, r = lane & 15;
    const int wm = wave & 1, wn = wave >> 1;
    const int Lrow = lane >> 3, Lseg = lane & 7;

    floatx4 acc[4][2];
    #pragma unroll
    for (int i = 0; i < 4; ++i)
        #pragma unroll
        for (int j = 0; j < 2; ++j) acc[i][j] = (floatx4)0.f;

    auto STAGE = [&](int kt, int buf) {              // 24 chunks: 16 A + 8 B, 6/wave
        int kb = kt * 64;
        #pragma unroll
        for (int i = 0; i < 6; ++i) {
            int c = wave * 6 + i;
            u16* dst = &stage[buf][c * 512];         // wave-uniform base + lane*16B
            const u16* src = (c < 16)
                ? A  + (size_t)(m0 + c * 8 + Lrow) * DIM + kb + ((Lseg ^ Lrow) * 8)
                : Bt + (size_t)(n0 + (c - 16) * 8 + Lrow) * DIM + kb + ((Lseg ^ Lrow) * 8);
            async16(src, dst);
        }
    };
    auto COMPUTE = [&](int buf) {
        const u16* As = &stage[buf][0];
        const u16* Bs = &stage[buf][8192];
        #pragma unroll
        for (int s = 0; s < 2; ++s) {               // two K=32 sub-steps
            int j0 = s * 4 + q;
            short8 bfr[2];
            #pragma unroll
            for (int nt = 0; nt < 2; ++nt) {
                int nl = wn * 32 + nt * 16 + r;
                bfr[nt] = *(const short8*)&Bs[nl * 64 + ((j0 ^ (nl & 7)) * 8)];
            }
            #pragma unroll
            for (int mt = 0; mt < 4; ++mt) {
                int ml = wm * 64 + mt * 16 + r;
                short8 afr = *(const short8*)&As[ml * 64 + ((j0 ^ (ml & 7)) * 8)];
                #pragma unroll
                for (int nt = 0; nt < 2; ++nt)
                    acc[mt][nt] = __builtin_amdgcn_mfma_f32_16x16x32_bf16(afr, bfr[nt], acc[mt][nt], 0, 0, 0);
            }
        }
    };

    STAGE(0, 0);                                    // prologue: stage k=0 -> buf0

    #pragma unroll 1
    for (int k = 0; k < 16; ++k) {
        int cur = k & 1;
        __syncthreads();            // vmcnt(0): buf[cur] staged; lgkmcnt(0): prev reads done
        if (k < 15) STAGE(k + 1, cur ^ 1);          // prefetch flies during COMPUTE(k)
        COMPUTE(cur);
    }

    // epilogue: selu(acc + rs[m]*b[n]); C/D layout col=lane&15, row=q*4+rr
    float psum[2] = {0.f, 0.f};
    float bv[2];
    #pragma unroll
    for (int nt = 0; nt < 2; ++nt) bv[nt] = bias[n0 + wn * 32 + nt * 16 + r];
    #pragma unroll
    for (int mt = 0; mt < 4; ++mt) {
        #pragma unroll
        for (int rr = 0; rr < 4; ++rr) {
            int m = m0 + wm * 64 + mt * 16 + q * 4 + rr;
            float rsm = rs[m];
            #pragma unroll
            for (int nt = 0; nt < 2; ++nt) {
                float v = selu_f(acc[mt][nt][rr] + rsm * bv[nt]);
                if (mode == 0)
                    H[(size_t)m * DIM + n0 + wn * 32 + nt * 16 + r] = f2bf(v);
                else psum[nt] += v;
            }
        }
    }
    if (mode) {                                     // column partial sums -> pooled
        float* PL = (float*)&stage[0][0];           // k=15 read stage[1]; stage[0] idle
        #pragma unroll
        for (int nt = 0; nt < 2; ++nt)
            PL[(wn * 32 + nt * 16 + r) * 8 + wm * 4 + q] = psum[nt];
        __syncthreads();
        if (t < 64) {
            float s = 0.f;
            #pragma unroll
            for (int i = 0; i < 8; ++i) s += PL[t * 8 + i];
            atomicAdd(&pooled[n0 + t], s);
        }
    }
}

// ---- FC head: 32-block k-split fc1; last block runs fc2 ---------------------
__global__ void k_fc(const float* __restrict__ pooled, const float* __restrict__ fcw1,
                     const float* __restrict__ fcb1, const float* __restrict__ fcw2,
                     const float* __restrict__ fcb2, float* __restrict__ zacc,
                     u32* __restrict__ cnt, float* __restrict__ out) {
    __shared__ float red[1024];
    __shared__ int lastf;
    int o = threadIdx.x, b = blockIdx.x;
    int kb = b * 32;
    float s = 0.f;
    #pragma unroll 4
    for (int kk = 0; kk < 32; ++kk)
        s += pooled[kb + kk] * fcw1[(size_t)(kb + kk) * FC1N + o];
    atomicAdd(&zacc[o], s * (1.f / NND));
    __threadfence();
    __syncthreads();
    if (o == 0) lastf = (atomicAdd(cnt, 1u) == 31u);
    __syncthreads();
    if (!lastf) return;
    __threadfence();
    float zv = atomicAdd(&zacc[o], 0.f);            // L2 read (bypass stale L1)
    float z = selu_f(zv + fcb1[o]);
    red[o] = z * fcw2[o * 2 + 0];
    red[512 + o] = z * fcw2[o * 2 + 1];
    __syncthreads();
    #pragma unroll 1
    for (int s2 = 256; s2 > 0; s2 >>= 1) {
        if (o < s2) { red[o] += red[o + s2]; red[512 + o] += red[512 + o + s2]; }
        __syncthreads();
    }
    if (o == 0) { out[0] = red[0] + fcb2[0]; out[1] = red[1] + fcb2[1]; }
}

extern "C" void kernel_launch(void* const* d_in, const int* in_sizes, int n_in,
                              void* d_out, int out_size, void* d_ws, size_t ws_size,
                              hipStream_t stream) {
    const float* x     = (const float*)d_in[0];
    const float* fw    = (const float*)d_in[1];
    const float* bw    = (const float*)d_in[2];
    const float* gc_w1 = (const float*)d_in[3];
    const float* gc_b1 = (const float*)d_in[4];
    const float* gc_w2 = (const float*)d_in[5];
    const float* gc_b2 = (const float*)d_in[6];
    const float* fc_w1 = (const float*)d_in[7];
    const float* fc_b1 = (const float*)d_in[8];
    const float* fc_w2 = (const float*)d_in[9];
    const float* fc_b2 = (const float*)d_in[10];
    float* out = (float*)d_out;

    char* ws = (char*)d_ws;
    u16*   XA     = (u16*)(ws);                       // 8 MB  (Ahat @ X, bf16)
    u16*   H1     = (u16*)(ws + (8u  << 20));         // 8 MB
    u16*   H1A    = (u16*)(ws + (16u << 20));         // 8 MB  (Ahat @ H1, bf16)
    u16*   W1t    = (u16*)(ws + (24u << 20));         // 2 MB
    u16*   W2t    = (u16*)(ws + (26u << 20));         // 2 MB
    float* fzone  = (float*)(ws + (28u << 20));
    float* pooled = fzone;                            // 1024 f
    float* zacc   = fzone + 1024;                     // 512 f
    u32*   cnt    = (u32*)(fzone + 1536);             // 1 u32
    float* rs     = fzone + 2048;                     // 4096 f (rowsum of Ahat)

    k_prep<<<1041, 256, 0, stream>>>(x, gc_w1, gc_w2, fw, bw, XA, W1t, W2t, fzone);
    k_gemm<<<dim3(32, 16), 256, 0, stream>>>(XA, W1t, gc_b1, rs, H1, nullptr, 0);
    k_band<<<512, 256, 0, stream>>>(H1, H1A, fw, bw);
    k_gemm<<<dim3(32, 16), 256, 0, stream>>>(H1A, W2t, gc_b2, rs, nullptr, pooled, 1);
    k_fc<<<32, 512, 0, stream>>>(pooled, fc_w1, fc_b1, fc_w2, fc_b2, zacc, cnt, out);
}

// Round 9
// 140.839 us; speedup vs baseline: 1.0139x; 1.0139x over previous
//
#include <hip/hip_runtime.h>
#include <stdint.h>

#define NND 4096
#define DIM 1024      // D = GC1 = GC2
#define FC1N 512

typedef __attribute__((ext_vector_type(8))) short short8;
typedef __attribute__((ext_vector_type(4))) float floatx4;
typedef unsigned short u16;
typedef unsigned int u32;

__device__ __forceinline__ u16 f2bf(float f) {
    union { float f; u32 u; } a; a.f = f;
    u32 u = a.u;
    return (u16)((u + 0x7fffu + ((u >> 16) & 1u)) >> 16);   // RNE
}
__device__ __forceinline__ float bf2f(u16 h) {
    union { u32 u; float f; } a; a.u = ((u32)h) << 16; return a.f;
}
__device__ __forceinline__ float selu_f(float x) {
    const float lam = 1.0507009873554805f;
    const float alp = 1.6732632423543772f;
    return x > 0.f ? lam * x : lam * alp * (expf(x) - 1.f);
}
__device__ __forceinline__ void async16(const u16* g, u16* l) {
    __builtin_amdgcn_global_load_lds((const __attribute__((address_space(1))) u32*)g,
                                     (__attribute__((address_space(3))) u32*)l, 16, 0, 0);
}
// 1/sqrt(deg) for row i of the banded adjacency; 0 for out-of-range rows
__device__ __forceinline__ float dinv_row(int i, const float* fw, const float* bw) {
    if (i < 0 || i >= NND) return 0.f;
    float deg = 1.f;
    #pragma unroll
    for (int j = 0; j < 8; ++j) {
        if (i + j + 1 < NND) deg += fw[j];
        if (i - j - 1 >= 0)  deg += bw[j];
    }
    return 1.f / sqrtf(deg);
}

// ---- prep --------------------------------------------------------------------
// blocks 0..511   : XA = Ahat @ X (fp32 -> bf16), 32 rows x 256 cols per block
// blocks 512..1023: W1/W2 transpose [K][N]fp32 -> [N][K]bf16, 64x64 tiles
// block 1024      : zero pooled/zacc/cnt
// blocks 1025..1040: rs[i] = rowsum(Ahat), 256 rows per block (parallel)
__global__ void k_prep(const float* __restrict__ x, const float* __restrict__ w1,
                       const float* __restrict__ w2, const float* __restrict__ fw,
                       const float* __restrict__ bw, u16* __restrict__ XA,
                       u16* __restrict__ W1t, u16* __restrict__ W2t,
                       float* __restrict__ fzone) {
    __shared__ __align__(16) char smem[49152];
    int b = blockIdx.x, t = threadIdx.x;
    if (b < 512) {                                   // row-band stencil on X
        __shared__ float sdv_s[48];
        __shared__ float wts_s[17];
        int m0 = (b >> 2) * 32;
        int c0 = (b & 3) * 256;
        if (t < 48) sdv_s[t] = dinv_row(m0 - 8 + t, fw, bw);
        else if (t >= 64 && t < 81) {
            int o = t - 72;                          // -8..8
            wts_s[t - 64] = (o == 0) ? 1.f : (o > 0 ? fw[o - 1] : bw[-o - 1]);
        }
        float (*tile)[256] = (float(*)[256])smem;    // 48 rows x 256 cols fp32
        int seg = t & 7;
        {
            int row = t >> 3;                        // rows 0..31
            int g = m0 - 8 + row;
            g = g < 0 ? 0 : (g > NND - 1 ? NND - 1 : g);
            const float4* src = (const float4*)x + (size_t)g * 256 + (c0 >> 2);
            float4* trow = (float4*)tile[row];
            #pragma unroll
            for (int i = 0; i < 8; ++i) trow[seg + i * 8] = src[seg + i * 8];
        }
        if (t < 128) {
            int row = 32 + (t >> 3);                 // rows 32..47
            int g = m0 - 8 + row;
            g = g > NND - 1 ? NND - 1 : g;
            const float4* src = (const float4*)x + (size_t)g * 256 + (c0 >> 2);
            float4* trow = (float4*)tile[row];
            #pragma unroll
            for (int i = 0; i < 8; ++i) trow[seg + i * 8] = src[seg + i * 8];
        }
        __syncthreads();
        float w[17];
        #pragma unroll
        for (int o = 0; o < 17; ++o) w[o] = wts_s[o];
        float win[17];
        #pragma unroll
        for (int j = 0; j < 16; ++j) win[j] = sdv_s[j] * tile[j][t];
        #pragma unroll
        for (int rr = 0; rr < 32; ++rr) {
            win[(rr + 16) % 17] = sdv_s[rr + 16] * tile[rr + 16][t];
            float a = 0.f;
            #pragma unroll
            for (int o = 0; o < 17; ++o) a += w[o] * win[(rr + o) % 17];
            XA[(size_t)(m0 + rr) * DIM + c0 + t] = f2bf(a * sdv_s[8 + rr]);
        }
        return;
    }
    if (b == 1024) {                                 // zero scratch floats
        for (int i = t; i < 1537; i += 256) fzone[i] = 0.f;   // pooled+zacc+cnt
        return;
    }
    if (b >= 1025) {                                 // rs: 256 rows per block
        float* rs = fzone + 2048;
        float fwr[8], bwr[8];
        #pragma unroll
        for (int j = 0; j < 8; ++j) { fwr[j] = fw[j]; bwr[j] = bw[j]; }
        float* dv = (float*)smem;                    // dinv for i0-8 .. i0+263
        int i0 = (b - 1025) * 256;
        #pragma unroll
        for (int half = 0; half < 2; ++half) {
            int idx = t + half * 256;                // 0..511; need 0..271
            if (idx < 272) {
                int i = i0 - 8 + idx;
                float dvv = 0.f;
                if (i >= 0 && i < NND) {
                    float deg = 1.f;
                    #pragma unroll
                    for (int j = 0; j < 8; ++j) {
                        if (i + j + 1 < NND) deg += fwr[j];
                        if (i - j - 1 >= 0)  deg += bwr[j];
                    }
                    dvv = 1.f / sqrtf(deg);
                }
                dv[idx] = dvv;
            }
        }
        __syncthreads();
        float di = dv[t + 8];
        float s = di;
        #pragma unroll
        for (int k = 1; k <= 8; ++k)
            s += fwr[k - 1] * dv[t + 8 + k] + bwr[k - 1] * dv[t + 8 - k];
        rs[i0 + t] = di * s;
        return;
    }
    // transpose [K][N] fp32 -> [N][K] bf16, 64x64 tiles
    int job = b - 512;
    const float* in = (job & 256) ? w2 : w1;
    u16* out = (job & 256) ? W2t : W1t;
    int tl = job & 255;
    int r0 = (tl >> 4) * 64, c0 = (tl & 15) * 64;
    float (*tile)[65] = (float(*)[65])smem;          // 64x65 fp32 = 16.6 KB
    int cg = t & 15, rb = t >> 4;
    #pragma unroll
    for (int rr = 0; rr < 4; ++rr) {
        int row = rb + rr * 16;
        float4 v = *(const float4*)(in + (size_t)(r0 + row) * DIM + c0 + cg * 4);
        tile[row][cg * 4 + 0] = v.x; tile[row][cg * 4 + 1] = v.y;
        tile[row][cg * 4 + 2] = v.z; tile[row][cg * 4 + 3] = v.w;
    }
    __syncthreads();
    #pragma unroll
    for (int rr = 0; rr < 4; ++rr) {
        int nl = rb + rr * 16;
        int kl = cg * 4;
        ushort4 o;
        o.x = f2bf(tile[kl + 0][nl]); o.y = f2bf(tile[kl + 1][nl]);
        o.z = f2bf(tile[kl + 2][nl]); o.w = f2bf(tile[kl + 3][nl]);
        *(ushort4*)(out + (size_t)(c0 + nl) * DIM + r0 + kl) = o;
    }
}

// ---- band stencil on bf16 matrix: out = Ahat @ in  (between the two GEMMs) --
// 32 output rows x 256 cols per block (48-row input tile), grid 512.
__global__ void k_band(const u16* __restrict__ in, u16* __restrict__ outp,
                       const float* __restrict__ fw, const float* __restrict__ bw) {
    __shared__ __align__(16) u16 tile[48][256];      // 24 KB
    __shared__ float sdv_s[48];
    __shared__ float wts_s[17];
    int b = blockIdx.x, t = threadIdx.x;
    int m0 = (b >> 2) * 32;
    int c0 = (b & 3) * 256;
    if (t < 48) sdv_s[t] = dinv_row(m0 - 8 + t, fw, bw);
    else if (t >= 64 && t < 81) {
        int o = t - 72;
        wts_s[t - 64] = (o == 0) ? 1.f : (o > 0 ? fw[o - 1] : bw[-o - 1]);
    }
    int seg = t & 7;
    {
        int row = t >> 3;                            // rows 0..31
        int g = m0 - 8 + row;
        g = g < 0 ? 0 : (g > NND - 1 ? NND - 1 : g);
        const uint4* src = (const uint4*)(in + (size_t)g * DIM + c0);
        uint4* trow = (uint4*)tile[row];
        #pragma unroll
        for (int i = 0; i < 4; ++i) trow[seg + i * 8] = src[seg + i * 8];
    }
    if (t < 128) {
        int row = 32 + (t >> 3);                     // rows 32..47
        int g = m0 - 8 + row;
        g = g > NND - 1 ? NND - 1 : g;
        const uint4* src = (const uint4*)(in + (size_t)g * DIM + c0);
        uint4* trow = (uint4*)tile[row];
        #pragma unroll
        for (int i = 0; i < 4; ++i) trow[seg + i * 8] = src[seg + i * 8];
    }
    __syncthreads();
    float w[17];
    #pragma unroll
    for (int o = 0; o < 17; ++o) w[o] = wts_s[o];
    float win[17];
    #pragma unroll
    for (int j = 0; j < 16; ++j) win[j] = sdv_s[j] * bf2f(tile[j][t]);
    #pragma unroll
    for (int rr = 0; rr < 32; ++rr) {
        win[(rr + 16) % 17] = sdv_s[rr + 16] * bf2f(tile[rr + 16][t]);
        float a = 0.f;
        #pragma unroll
        for (int o = 0; o < 17; ++o) a += w[o] * win[(rr + o) % 17];
        outp[(size_t)(m0 + rr) * DIM + c0 + t] = f2bf(a * sdv_s[8 + rr]);
    }
}

// ---- 64x64 bf16 GEMM tile, double-buffered, plain __syncthreads -------------
// H[m,n] = selu(acc + rs[m]*bias[n]). mode 0: write bf16 H. mode 1: mean-pool.
// Grid (64,16)=1024 blocks = 4 blocks/CU (launch_bounds 256,4; 32 KB LDS x4 =
// 128 KB <= 160 KB). 16 waves/CU (4/SIMD): at any instant ~3 blocks compute
// while 1 stages — cross-block overlap (m114) hides the barrier drain.
// 4 waves 2Mx2N (wave tile 32x32, acc 2x2). BK=64, prefetch k+1 into buf^1.
__launch_bounds__(256, 4)
__global__ void k_gemm(const u16* __restrict__ A, const u16* __restrict__ Bt,
                       const float* __restrict__ bias, const float* __restrict__ rs,
                       u16* __restrict__ H, float* __restrict__ pooled, int mode) {
    __shared__ __align__(16) u16 stage[2][8192];    // 2 x (A 64x64 | B 64x64) = 32 KB
    const int m0 = blockIdx.x * 64, n0 = blockIdx.y * 64;
    const int t = threadIdx.x, wave = t >> 6, lane = t & 63;
    const int q = lane >> 4, r = lane & 15;
    const int wm = wave & 1, wn = wave >> 1;
    const int Lrow = lane >> 3, Lseg = lane & 7;

    floatx4 acc[2][2];
    #pragma unroll
    for (int i = 0; i < 2; ++i)
        #pragma unroll
        for (int j = 0; j < 2; ++j) acc[i][j] = (floatx4)0.f;

    auto STAGE = [&](int kt, int buf) {              // 16 chunks: 8 A + 8 B, 4/wave
        int kb = kt * 64;
        #pragma unroll
        for (int i = 0; i < 4; ++i) {
            int c = wave * 4 + i;
            u16* dst = &stage[buf][c * 512];         // wave-uniform base + lane*16B
            const u16* src = (c < 8)
                ? A  + (size_t)(m0 + c * 8 + Lrow) * DIM + kb + ((Lseg ^ Lrow) * 8)
                : Bt + (size_t)(n0 + (c - 8) * 8 + Lrow) * DIM + kb + ((Lseg ^ Lrow) * 8);
            async16(src, dst);
        }
    };
    auto COMPUTE = [&](int buf) {
        const u16* As = &stage[buf][0];
        const u16* Bs = &stage[buf][4096];
        #pragma unroll
        for (int s = 0; s < 2; ++s) {               // two K=32 sub-steps
            int j0 = s * 4 + q;
            short8 bfr[2];
            #pragma unroll
            for (int nt = 0; nt < 2; ++nt) {
                int nl = wn * 32 + nt * 16 + r;
                bfr[nt] = *(const short8*)&Bs[nl * 64 + ((j0 ^ (nl & 7)) * 8)];
            }
            #pragma unroll
            for (int mt = 0; mt < 2; ++mt) {
                int ml = wm * 32 + mt * 16 + r;
                short8 afr = *(const short8*)&As[ml * 64 + ((j0 ^ (ml & 7)) * 8)];
                #pragma unroll
                for (int nt = 0; nt < 2; ++nt)
                    acc[mt][nt] = __builtin_amdgcn_mfma_f32_16x16x32_bf16(afr, bfr[nt], acc[mt][nt], 0, 0, 0);
            }
        }
    };

    STAGE(0, 0);                                    // prologue: stage k=0 -> buf0

    #pragma unroll 1
    for (int k = 0; k < 16; ++k) {
        int cur = k & 1;
        __syncthreads();            // vmcnt(0): buf[cur] staged; lgkmcnt(0): prev reads done
        if (k < 15) STAGE(k + 1, cur ^ 1);          // prefetch flies during COMPUTE(k)
        COMPUTE(cur);
    }

    // epilogue: selu(acc + rs[m]*b[n]); C/D layout col=lane&15, row=q*4+rr
    float psum[2] = {0.f, 0.f};
    float bv[2];
    #pragma unroll
    for (int nt = 0; nt < 2; ++nt) bv[nt] = bias[n0 + wn * 32 + nt * 16 + r];
    #pragma unroll
    for (int mt = 0; mt < 2; ++mt) {
        #pragma unroll
        for (int rr = 0; rr < 4; ++rr) {
            int m = m0 + wm * 32 + mt * 16 + q * 4 + rr;
            float rsm = rs[m];
            #pragma unroll
            for (int nt = 0; nt < 2; ++nt) {
                float v = selu_f(acc[mt][nt][rr] + rsm * bv[nt]);
                if (mode == 0)
                    H[(size_t)m * DIM + n0 + wn * 32 + nt * 16 + r] = f2bf(v);
                else psum[nt] += v;
            }
        }
    }
    if (mode) {                                     // column partial sums -> pooled
        float* PL = (float*)&stage[0][0];           // k=15 read stage[1]; stage[0] idle
        #pragma unroll
        for (int nt = 0; nt < 2; ++nt)
            PL[(wn * 32 + nt * 16 + r) * 8 + wm * 4 + q] = psum[nt];
        __syncthreads();
        if (t < 64) {
            float s = 0.f;
            #pragma unroll
            for (int i = 0; i < 8; ++i) s += PL[t * 8 + i];
            atomicAdd(&pooled[n0 + t], s);
        }
    }
}

// ---- FC head: 32-block k-split fc1; last block runs fc2 ---------------------
__global__ void k_fc(const float* __restrict__ pooled, const float* __restrict__ fcw1,
                     const float* __restrict__ fcb1, const float* __restrict__ fcw2,
                     const float* __restrict__ fcb2, float* __restrict__ zacc,
                     u32* __restrict__ cnt, float* __restrict__ out) {
    __shared__ float red[1024];
    __shared__ int lastf;
    int o = threadIdx.x, b = blockIdx.x;
    int kb = b * 32;
    float s = 0.f;
    #pragma unroll 4
    for (int kk = 0; kk < 32; ++kk)
        s += pooled[kb + kk] * fcw1[(size_t)(kb + kk) * FC1N + o];
    atomicAdd(&zacc[o], s * (1.f / NND));
    __threadfence();
    __syncthreads();
    if (o == 0) lastf = (atomicAdd(cnt, 1u) == 31u);
    __syncthreads();
    if (!lastf) return;
    __threadfence();
    float zv = atomicAdd(&zacc[o], 0.f);            // L2 read (bypass stale L1)
    float z = selu_f(zv + fcb1[o]);
    red[o] = z * fcw2[o * 2 + 0];
    red[512 + o] = z * fcw2[o * 2 + 1];
    __syncthreads();
    #pragma unroll 1
    for (int s2 = 256; s2 > 0; s2 >>= 1) {
        if (o < s2) { red[o] += red[o + s2]; red[512 + o] += red[512 + o + s2]; }
        __syncthreads();
    }
    if (o == 0) { out[0] = red[0] + fcb2[0]; out[1] = red[1] + fcb2[1]; }
}

extern "C" void kernel_launch(void* const* d_in, const int* in_sizes, int n_in,
                              void* d_out, int out_size, void* d_ws, size_t ws_size,
                              hipStream_t stream) {
    const float* x     = (const float*)d_in[0];
    const float* fw    = (const float*)d_in[1];
    const float* bw    = (const float*)d_in[2];
    const float* gc_w1 = (const float*)d_in[3];
    const float* gc_b1 = (const float*)d_in[4];
    const float* gc_w2 = (const float*)d_in[5];
    const float* gc_b2 = (const float*)d_in[6];
    const float* fc_w1 = (const float*)d_in[7];
    const float* fc_b1 = (const float*)d_in[8];
    const float* fc_w2 = (const float*)d_in[9];
    const float* fc_b2 = (const float*)d_in[10];
    float* out = (float*)d_out;

    char* ws = (char*)d_ws;
    u16*   XA     = (u16*)(ws);                       // 8 MB  (Ahat @ X, bf16)
    u16*   H1     = (u16*)(ws + (8u  << 20));         // 8 MB
    u16*   H1A    = (u16*)(ws + (16u << 20));         // 8 MB  (Ahat @ H1, bf16)
    u16*   W1t    = (u16*)(ws + (24u << 20));         // 2 MB
    u16*   W2t    = (u16*)(ws + (26u << 20));         // 2 MB
    float* fzone  = (float*)(ws + (28u << 20));
    float* pooled = fzone;                            // 1024 f
    float* zacc   = fzone + 1024;                     // 512 f
    u32*   cnt    = (u32*)(fzone + 1536);             // 1 u32
    float* rs     = fzone + 2048;                     // 4096 f (rowsum of Ahat)

    k_prep<<<1041, 256, 0, stream>>>(x, gc_w1, gc_w2, fw, bw, XA, W1t, W2t, fzone);
    k_gemm<<<dim3(64, 16), 256, 0, stream>>>(XA, W1t, gc_b1, rs, H1, nullptr, 0);
    k_band<<<512, 256, 0, stream>>>(H1, H1A, fw, bw);
    k_gemm<<<dim3(64, 16), 256, 0, stream>>>(H1A, W2t, gc_b2, rs, nullptr, pooled, 1);
    k_fc<<<32, 512, 0, stream>>>(pooled, fc_w1, fc_b1, fc_w2, fc_b2, zacc, cnt, out);
}